// Round 3
// baseline (395.609 us; speedup 1.0000x reference)
//
#include <hip/hip_runtime.h>
#include <hip/hip_bf16.h>

// B=16, NQ=NK=784, D_MODEL=512, H=8, DK=DV=64
#define SZX ((size_t)12544 * 512)   // elements of one [B*784, 512] matrix
#define WSEG ((size_t)262144)       // one 512x512 weight

typedef __attribute__((ext_vector_type(8))) short short8;
typedef __attribute__((ext_vector_type(4))) short short4s;
typedef __attribute__((ext_vector_type(4))) float floatx4;

typedef const __attribute__((address_space(1))) void* gas_cvp;
typedef __attribute__((address_space(3))) void* las_vp;

__device__ __forceinline__ void gl_lds16(const void* g, void* l) {
    __builtin_amdgcn_global_load_lds((gas_cvp)g, (las_vp)l, 16, 0, 0);
}

__device__ __forceinline__ unsigned short f2bf(float f) {
    unsigned int u = __float_as_uint(f);
    u += 0x7fffu + ((u >> 16) & 1u);   // RNE
    return (unsigned short)(u >> 16);
}

__device__ __forceinline__ unsigned int pack2bf(float a, float b) {
    __hip_bfloat162 h = __float22bfloat162_rn(float2{a, b});  // v_cvt_pk_bf16_f32 on gfx950
    return *(unsigned int*)&h;
}

__device__ __forceinline__ short8 lds_read8(const unsigned short* p) {
    // 8B-aligned LDS read as two b64s (this exact pattern measured 0 bank conflicts)
    short4s a = *(const short4s*)p;
    short4s b = *(const short4s*)(p + 4);
    return __builtin_shufflevector(a, b, 0, 1, 2, 3, 4, 5, 6, 7);
}

#define MFMA16(a, b, c) __builtin_amdgcn_mfma_f32_16x16x32_bf16(a, b, c, 0, 0, 0)

// ---------------- f32 -> bf16 convert, 3 tensors in one dispatch ------------------
__global__ void cvt3(const float* __restrict__ q, const float* __restrict__ k,
                     const float* __restrict__ v,
                     unsigned short* __restrict__ xq, unsigned short* __restrict__ xk,
                     unsigned short* __restrict__ xv, int which) {
    int sel = blockIdx.y + which;
    const float* in = sel == 0 ? q : sel == 1 ? k : v;
    unsigned short* out = sel == 0 ? xq : sel == 1 ? xk : xv;
    size_t i = ((size_t)blockIdx.x * blockDim.x + threadIdx.x) * 4;
    float4 vv = *(const float4*)(in + i);
    ushort4 o = make_ushort4(f2bf(vv.x), f2bf(vv.y), f2bf(vv.z), f2bf(vv.w));
    *(ushort4*)(out + i) = o;
}

// ---------------- weight transpose + convert: Wt[o][i] = bf16(W[i][o]) ------------
__global__ void transpose_cvt(const float* __restrict__ W0, const float* __restrict__ W1,
                              const float* __restrict__ W2, const float* __restrict__ W3,
                              unsigned short* __restrict__ out) {
    __shared__ float tile[32][33];
    const float* W = blockIdx.z == 0 ? W0 : blockIdx.z == 1 ? W1 : blockIdx.z == 2 ? W2 : W3;
    unsigned short* O = out + (size_t)blockIdx.z * WSEG;
    int x = blockIdx.x * 32 + threadIdx.x;
    int y0 = blockIdx.y * 32;
    for (int k = threadIdx.y; k < 32; k += 8)
        tile[k][threadIdx.x] = W[(size_t)(y0 + k) * 512 + x];
    __syncthreads();
    int xo = blockIdx.y * 32 + threadIdx.x;
    int yo0 = blockIdx.x * 32;
    for (int k = threadIdx.y; k < 32; k += 8)
        O[(size_t)(yo0 + k) * 512 + xo] = f2bf(tile[threadIdx.x][k]);
}

// ---------------- merged QKV projection GEMM (128x128 tiles) ----------------------
__global__ __launch_bounds__(256) void gemm_qkv(
    const unsigned short* __restrict__ Xq, const unsigned short* __restrict__ Xk,
    const unsigned short* __restrict__ Xv, const unsigned short* __restrict__ Wt,
    const float* __restrict__ bq, const float* __restrict__ bk, const float* __restrict__ bv,
    unsigned short* __restrict__ Qb, unsigned short* __restrict__ Kb,
    unsigned short* __restrict__ Vtb, int zoff)
{
    __shared__ unsigned short Als[128 * 32];
    __shared__ unsigned short Bls[128 * 32];
    int z = blockIdx.z + zoff;
    const unsigned short* X = z == 0 ? Xq : z == 1 ? Xk : Xv;
    const unsigned short* Wz = Wt + (size_t)z * WSEG;
    const float* bias = z == 0 ? bq : z == 1 ? bk : bv;

    int tid = threadIdx.x;
    int lane = tid & 63, wave = tid >> 6;
    int wm = wave & 1, wn = wave >> 1;
    int c16 = lane & 15, g = lane >> 4;
    int tm, tn;
    const unsigned short *Abase, *Bbase;
    if (z < 2) { tm = blockIdx.x; tn = blockIdx.y; Abase = X + (size_t)tm * 128 * 512; Bbase = Wz + (size_t)tn * 128 * 512; }
    else       { tm = blockIdx.y; tn = blockIdx.x; Abase = Wz + (size_t)tm * 128 * 512; Bbase = X + (size_t)tn * 128 * 512; }

    floatx4 acc[4][4];
#pragma unroll
    for (int i = 0; i < 4; i++)
#pragma unroll
        for (int j = 0; j < 4; j++) acc[i][j] = (floatx4){0.f, 0.f, 0.f, 0.f};

    for (int kb = 0; kb < 16; ++kb) {
        int k0 = kb * 32;
#pragma unroll
        for (int rep = 0; rep < 2; ++rep) {
            int slot = rep * 256 + tid;
            int row = slot >> 2, kp = slot & 3;
            gl_lds16(Abase + (size_t)row * 512 + k0 + kp * 8, &Als[slot * 8]);
            gl_lds16(Bbase + (size_t)row * 512 + k0 + kp * 8, &Bls[slot * 8]);
        }
        __syncthreads();
        short8 af[4], bfr[4];
#pragma unroll
        for (int i = 0; i < 4; i++)
            af[i] = *(const short8*)&Als[(wm * 64 + i * 16 + c16) * 32 + g * 8];
#pragma unroll
        for (int j = 0; j < 4; j++)
            bfr[j] = *(const short8*)&Bls[(wn * 64 + j * 16 + c16) * 32 + g * 8];
#pragma unroll
        for (int i = 0; i < 4; i++)
#pragma unroll
            for (int j = 0; j < 4; j++)
                acc[i][j] = MFMA16(af[i], bfr[j], acc[i][j]);
        __syncthreads();
    }

#pragma unroll
    for (int j = 0; j < 4; j++) {
        int n = tn * 128 + wn * 64 + j * 16 + c16;
        int bi = n / 784, nn = n - bi * 784;         // z==2 only
#pragma unroll
        for (int i = 0; i < 4; i++) {
#pragma unroll
            for (int r4 = 0; r4 < 4; r4++) {
                int m = tm * 128 + wm * 64 + i * 16 + g * 4 + r4;
                float v = acc[i][j][r4] + ((z < 2) ? bias[n] : bias[m]);
                if (z == 0)      Qb[(size_t)m * 512 + n] = f2bf(v);
                else if (z == 1) Kb[(size_t)m * 512 + n] = f2bf(v);
                else {
                    int h = m >> 6, d = m & 63;
                    Vtb[(((size_t)bi * 8 + h) * 64 + d) * 784 + nn] = f2bf(v);
                }
            }
        }
    }
}

// ---------------- output projection, swapped (64x128 tiles): out[b][c][q] f32 -----
__global__ __launch_bounds__(256) void gemm_out(
    const unsigned short* __restrict__ Wto, const unsigned short* __restrict__ ctx,
    const float* __restrict__ bo, float* __restrict__ out)
{
    __shared__ unsigned short Als[64 * 32];
    __shared__ unsigned short Bls[128 * 32];
    int tid = threadIdx.x;
    int lane = tid & 63, wn = tid >> 6;
    int c16 = lane & 15, g = lane >> 4;
    int tm = blockIdx.x, tn = blockIdx.y;

    const unsigned short* Abase = Wto + (size_t)tm * 64 * 512;
    const unsigned short* Bbase = ctx + (size_t)tn * 128 * 512;

    floatx4 acc[4][2];
#pragma unroll
    for (int i = 0; i < 4; i++)
#pragma unroll
        for (int j = 0; j < 2; j++) acc[i][j] = (floatx4){0.f, 0.f, 0.f, 0.f};

    for (int kb = 0; kb < 16; ++kb) {
        int k0 = kb * 32;
        {
            int row = tid >> 2, kp = tid & 3;
            gl_lds16(Abase + (size_t)row * 512 + k0 + kp * 8, &Als[tid * 8]);
        }
#pragma unroll
        for (int rep = 0; rep < 2; ++rep) {
            int slot = rep * 256 + tid;
            int row = slot >> 2, kp = slot & 3;
            gl_lds16(Bbase + (size_t)row * 512 + k0 + kp * 8, &Bls[slot * 8]);
        }
        __syncthreads();
        short8 af[4], bfr[2];
#pragma unroll
        for (int i = 0; i < 4; i++)
            af[i] = *(const short8*)&Als[(i * 16 + c16) * 32 + g * 8];
#pragma unroll
        for (int j = 0; j < 2; j++)
            bfr[j] = *(const short8*)&Bls[(wn * 32 + j * 16 + c16) * 32 + g * 8];
#pragma unroll
        for (int i = 0; i < 4; i++)
#pragma unroll
            for (int j = 0; j < 2; j++)
                acc[i][j] = MFMA16(af[i], bfr[j], acc[i][j]);
        __syncthreads();
    }

#pragma unroll
    for (int j = 0; j < 2; j++) {
        int n = tn * 128 + wn * 32 + j * 16 + c16;
        int bi = n / 784, q = n - bi * 784;
#pragma unroll
        for (int i = 0; i < 4; i++) {
#pragma unroll
            for (int r4 = 0; r4 < 4; r4++) {
                int m = tm * 64 + i * 16 + g * 4 + r4;
                out[((size_t)bi * 512 + m) * 784 + q] = acc[i][j][r4] + bo[m];
            }
        }
    }
}

// ---------------- fused attention v3: S^T form, 16 q-rows/wave --------------------
// block = 256 thr = 4 waves = 4 heads; grid (16 b, 49 qt, 2 hh).
// S^T = K·Q^T  =>  C-layout: row (g*4+r) = key, col c16 = q.
//   -> corr is ONE float4/lane per 16x16 subtile; P-write is ONE packed b64.
// P stored [q][key] in LDS (stride 68), read back as PV A-fragments.
__global__ __launch_bounds__(256, 4) void attn_kernel(
    const unsigned short* __restrict__ Qb,
    const unsigned short* __restrict__ Kb,
    const unsigned short* __restrict__ Vtb,
    const float* __restrict__ corr,
    unsigned short* __restrict__ ctx)
{
    __shared__ unsigned short Plds[4][16][68];   // [wave][q-row][key(64)+pad4]
    int b = blockIdx.x, qt = blockIdx.y, hh = blockIdx.z;
    int tid = threadIdx.x;
    int lane = tid & 63, w = tid >> 6;
    int h = hh * 4 + w;
    int c16 = lane & 15, g = lane >> 4;
    int q0 = qt * 16;   // 49*16 = 784: no q tail

    // Q fragment (B-operand of S^T): lane c16 = q, holds dk = g*8..g*8+7 (+32)
    short8 bq0, bq1;
    {
        const unsigned short* qp = Qb + (size_t)(b * 784 + q0 + c16) * 512 + h * 64 + g * 8;
        bq0 = *(const short8*)qp;
        bq1 = *(const short8*)(qp + 32);
    }

    floatx4 o[4];
#pragma unroll
    for (int nt = 0; nt < 4; nt++) o[nt] = (floatx4){0.f, 0.f, 0.f, 0.f};
    float l = 0.f;   // per-lane partial softmax denominator for q = c16

    const float* corrq = corr + ((size_t)b * 784 + (q0 + c16)) * 784;
    const unsigned short* Kh = Kb + (size_t)b * 784 * 512 + h * 64;
    const unsigned short* Vh = Vtb + ((size_t)(b * 8 + h)) * 64 * 784;

#pragma unroll 1
    for (int it = 0; it < 13; ++it) {
        int k0 = it * 64;
        // --- QK^T (transposed) + softmax-numerator, 4 subtiles of 16 keys ---
#pragma unroll
        for (int t = 0; t < 4; ++t) {
            int kbase = k0 + t * 16;                 // wave-uniform
            if (kbase < 784) {                        // all 16 keys of a valid subtile are in-range
                const unsigned short* kp = Kh + (size_t)(kbase + c16) * 512 + g * 8;
                short8 a0 = *(const short8*)kp;
                short8 a1 = *(const short8*)(kp + 32);
                floatx4 st = (floatx4){0.f, 0.f, 0.f, 0.f};
                st = MFMA16(a0, bq0, st);
                st = MFMA16(a1, bq1, st);
                float4 cv = *(const float4*)(corrq + kbase + g * 4);
                float e0 = __expf(fmaf(st[0], 0.125f, cv.x));
                float e1 = __expf(fmaf(st[1], 0.125f, cv.y));
                float e2 = __expf(fmaf(st[2], 0.125f, cv.z));
                float e3 = __expf(fmaf(st[3], 0.125f, cv.w));
                l += (e0 + e1) + (e2 + e3);
                uint2 w2 = make_uint2(pack2bf(e0, e1), pack2bf(e2, e3));
                *(uint2*)&Plds[w][c16][t * 16 + g * 4] = w2;
            } else {
                *(uint2*)&Plds[w][c16][t * 16 + g * 4] = make_uint2(0u, 0u);
            }
        }
        // --- P·V (wave-private LDS round-trip, in-order DS, no barrier) ---
        const unsigned short* prow = &Plds[w][c16][0];
        short8 pa0 = lds_read8(prow + g * 8);
        short8 pa1 = lds_read8(prow + 32 + g * 8);
#pragma unroll
        for (int nt = 0; nt < 4; ++nt) {
            int d = nt * 16 + c16;
            const unsigned short* vp = Vh + (size_t)d * 784 + k0 + g * 8;
            short8 v0 = *(const short8*)vp;
            short8 v1 = *(const short8*)(vp + 32);
            o[nt] = MFMA16(pa0, v0, o[nt]);
            o[nt] = MFMA16(pa1, v1, o[nt]);
        }
    }

    // reduce l over the 4 g-groups (lanes with same c16), invert, redistribute
    l += __shfl_xor(l, 16);
    l += __shfl_xor(l, 32);
    float inv = 1.0f / l;
    float invr[4];
#pragma unroll
    for (int r = 0; r < 4; ++r) invr[r] = __shfl(inv, g * 4 + r);

#pragma unroll
    for (int nt = 0; nt < 4; ++nt)
#pragma unroll
        for (int r = 0; r < 4; ++r) {
            int row = q0 + g * 4 + r;
            ctx[(size_t)(b * 784 + row) * 512 + h * 64 + nt * 16 + c16] =
                f2bf(o[nt][r] * invr[r]);
        }
}

extern "C" void kernel_launch(void* const* d_in, const int* in_sizes, int n_in,
                              void* d_out, int out_size, void* d_ws, size_t ws_size,
                              hipStream_t stream) {
    (void)in_sizes; (void)n_in; (void)out_size;
    const float* queries = (const float*)d_in[0];
    const float* keys    = (const float*)d_in[1];
    const float* values  = (const float*)d_in[2];
    const float* corr    = (const float*)d_in[3];
    const float* Wq = (const float*)d_in[4];
    const float* bq = (const float*)d_in[5];
    const float* Wk = (const float*)d_in[6];
    const float* bk = (const float*)d_in[7];
    const float* Wv = (const float*)d_in[8];
    const float* bv = (const float*)d_in[9];
    const float* Wo = (const float*)d_in[10];
    const float* bo = (const float*)d_in[11];

    size_t need = (6 * SZX + 4 * WSEG) * 2;
    if (ws_size >= need) {
        unsigned short* Xq  = (unsigned short*)d_ws;     // later reused as ctx
        unsigned short* Xk  = Xq + SZX;
        unsigned short* Xv  = Xk + SZX;
        unsigned short* Qb  = Xv + SZX;
        unsigned short* Kb  = Qb + SZX;
        unsigned short* Vtb = Kb + SZX;
        unsigned short* Wt  = Vtb + SZX;

        transpose_cvt<<<dim3(16, 16, 4), dim3(32, 8), 0, stream>>>(Wq, Wk, Wv, Wo, Wt);
        cvt3<<<dim3(6272, 3), 256, 0, stream>>>(queries, keys, values, Xq, Xk, Xv, 0);
        gemm_qkv<<<dim3(98, 4, 3), 256, 0, stream>>>(Xq, Xk, Xv, Wt, bq, bk, bv, Qb, Kb, Vtb, 0);
        attn_kernel<<<dim3(16, 49, 2), 256, 0, stream>>>(Qb, Kb, Vtb, corr, Xq);
        gemm_out<<<dim3(8, 98), 256, 0, stream>>>(Wt + 3 * WSEG, Xq, bo, (float*)d_out);
    } else {
        // sequential fallback with a single shared X buffer
        unsigned short* X   = (unsigned short*)d_ws;
        unsigned short* Qb  = X + SZX;
        unsigned short* Kb  = Qb + SZX;
        unsigned short* Vtb = Kb + SZX;
        unsigned short* Wt  = Vtb + SZX;

        transpose_cvt<<<dim3(16, 16, 4), dim3(32, 8), 0, stream>>>(Wq, Wk, Wv, Wo, Wt);
        for (int z = 0; z < 3; ++z) {
            cvt3<<<dim3(6272, 1), 256, 0, stream>>>(queries, keys, values, X, X, X, z);
            gemm_qkv<<<dim3(98, 4, 1), 256, 0, stream>>>(X, X, X, Wt, bq, bk, bv, Qb, Kb, Vtb, z);
        }
        attn_kernel<<<dim3(16, 49, 2), 256, 0, stream>>>(Qb, Kb, Vtb, corr, X);
        gemm_out<<<dim3(8, 98), 256, 0, stream>>>(Wt + 3 * WSEG, X, bo, (float*)d_out);
    }
}

// Round 4
// 339.596 us; speedup vs baseline: 1.1649x; 1.1649x over previous
//
#include <hip/hip_runtime.h>
#include <hip/hip_bf16.h>

// B=16, NQ=NK=784, D_MODEL=512, H=8, DK=DV=64
#define SZX ((size_t)12544 * 512)   // elements of one [B*784, 512] matrix
#define WSEG ((size_t)262144)       // one 512x512 weight

typedef __attribute__((ext_vector_type(8))) short short8;
typedef __attribute__((ext_vector_type(4))) short short4s;
typedef __attribute__((ext_vector_type(4))) float floatx4;

typedef const __attribute__((address_space(1))) void* gas_cvp;
typedef __attribute__((address_space(3))) void* las_vp;

__device__ __forceinline__ void gl_lds16(const void* g, void* l) {
    __builtin_amdgcn_global_load_lds((gas_cvp)g, (las_vp)l, 16, 0, 0);
}

__device__ __forceinline__ unsigned short f2bf(float f) {
    unsigned int u = __float_as_uint(f);
    u += 0x7fffu + ((u >> 16) & 1u);   // RNE
    return (unsigned short)(u >> 16);
}

__device__ __forceinline__ unsigned int pack2bf(float a, float b) {
    __hip_bfloat162 h = __float22bfloat162_rn(float2{a, b});  // v_cvt_pk_bf16_f32
    return *(unsigned int*)&h;
}

__device__ __forceinline__ short8 lds_read8(const unsigned short* p) {
    // 8B-aligned LDS read as two b64s (measured 0 bank conflicts in R2/R3)
    short4s a = *(const short4s*)p;
    short4s b = *(const short4s*)(p + 4);
    return __builtin_shufflevector(a, b, 0, 1, 2, 3, 4, 5, 6, 7);
}

#define MFMA16(a, b, c) __builtin_amdgcn_mfma_f32_16x16x32_bf16(a, b, c, 0, 0, 0)

// ---------------- f32 -> bf16 convert, 3 tensors in one dispatch ------------------
__global__ void cvt3(const float* __restrict__ q, const float* __restrict__ k,
                     const float* __restrict__ v,
                     unsigned short* __restrict__ xq, unsigned short* __restrict__ xk,
                     unsigned short* __restrict__ xv, int which) {
    int sel = blockIdx.y + which;
    const float* in = sel == 0 ? q : sel == 1 ? k : v;
    unsigned short* out = sel == 0 ? xq : sel == 1 ? xk : xv;
    size_t i = ((size_t)blockIdx.x * blockDim.x + threadIdx.x) * 4;
    float4 vv = *(const float4*)(in + i);
    ushort4 o = make_ushort4(f2bf(vv.x), f2bf(vv.y), f2bf(vv.z), f2bf(vv.w));
    *(ushort4*)(out + i) = o;
}

// ---------------- weight transpose + convert: Wt[o][i] = bf16(W[i][o]) ------------
__global__ void transpose_cvt(const float* __restrict__ W0, const float* __restrict__ W1,
                              const float* __restrict__ W2, const float* __restrict__ W3,
                              unsigned short* __restrict__ out) {
    __shared__ float tile[32][33];
    const float* W = blockIdx.z == 0 ? W0 : blockIdx.z == 1 ? W1 : blockIdx.z == 2 ? W2 : W3;
    unsigned short* O = out + (size_t)blockIdx.z * WSEG;
    int x = blockIdx.x * 32 + threadIdx.x;
    int y0 = blockIdx.y * 32;
    for (int k = threadIdx.y; k < 32; k += 8)
        tile[k][threadIdx.x] = W[(size_t)(y0 + k) * 512 + x];
    __syncthreads();
    int xo = blockIdx.y * 32 + threadIdx.x;
    int yo0 = blockIdx.x * 32;
    for (int k = threadIdx.y; k < 32; k += 8)
        O[(size_t)(yo0 + k) * 512 + xo] = f2bf(tile[threadIdx.x][k]);
}

// ---------------- merged QKV projection GEMM (128x128 tiles) ----------------------
__global__ __launch_bounds__(256) void gemm_qkv(
    const unsigned short* __restrict__ Xq, const unsigned short* __restrict__ Xk,
    const unsigned short* __restrict__ Xv, const unsigned short* __restrict__ Wt,
    const float* __restrict__ bq, const float* __restrict__ bk, const float* __restrict__ bv,
    unsigned short* __restrict__ Qb, unsigned short* __restrict__ Kb,
    unsigned short* __restrict__ Vtb, int zoff)
{
    __shared__ unsigned short Als[128 * 32];
    __shared__ unsigned short Bls[128 * 32];
    int z = blockIdx.z + zoff;
    const unsigned short* X = z == 0 ? Xq : z == 1 ? Xk : Xv;
    const unsigned short* Wz = Wt + (size_t)z * WSEG;
    const float* bias = z == 0 ? bq : z == 1 ? bk : bv;

    int tid = threadIdx.x;
    int lane = tid & 63, wave = tid >> 6;
    int wm = wave & 1, wn = wave >> 1;
    int c16 = lane & 15, g = lane >> 4;
    int tm, tn;
    const unsigned short *Abase, *Bbase;
    if (z < 2) { tm = blockIdx.x; tn = blockIdx.y; Abase = X + (size_t)tm * 128 * 512; Bbase = Wz + (size_t)tn * 128 * 512; }
    else       { tm = blockIdx.y; tn = blockIdx.x; Abase = Wz + (size_t)tm * 128 * 512; Bbase = X + (size_t)tn * 128 * 512; }

    floatx4 acc[4][4];
#pragma unroll
    for (int i = 0; i < 4; i++)
#pragma unroll
        for (int j = 0; j < 4; j++) acc[i][j] = (floatx4){0.f, 0.f, 0.f, 0.f};

    for (int kb = 0; kb < 16; ++kb) {
        int k0 = kb * 32;
#pragma unroll
        for (int rep = 0; rep < 2; ++rep) {
            int slot = rep * 256 + tid;
            int row = slot >> 2, kp = slot & 3;
            gl_lds16(Abase + (size_t)row * 512 + k0 + kp * 8, &Als[slot * 8]);
            gl_lds16(Bbase + (size_t)row * 512 + k0 + kp * 8, &Bls[slot * 8]);
        }
        __syncthreads();
        short8 af[4], bfr[4];
#pragma unroll
        for (int i = 0; i < 4; i++)
            af[i] = *(const short8*)&Als[(wm * 64 + i * 16 + c16) * 32 + g * 8];
#pragma unroll
        for (int j = 0; j < 4; j++)
            bfr[j] = *(const short8*)&Bls[(wn * 64 + j * 16 + c16) * 32 + g * 8];
#pragma unroll
        for (int i = 0; i < 4; i++)
#pragma unroll
            for (int j = 0; j < 4; j++)
                acc[i][j] = MFMA16(af[i], bfr[j], acc[i][j]);
        __syncthreads();
    }

#pragma unroll
    for (int j = 0; j < 4; j++) {
        int n = tn * 128 + wn * 64 + j * 16 + c16;
        int bi = n / 784, nn = n - bi * 784;         // z==2 only
#pragma unroll
        for (int i = 0; i < 4; i++) {
#pragma unroll
            for (int r4 = 0; r4 < 4; r4++) {
                int m = tm * 128 + wm * 64 + i * 16 + g * 4 + r4;
                float v = acc[i][j][r4] + ((z < 2) ? bias[n] : bias[m]);
                if (z == 0)      Qb[(size_t)m * 512 + n] = f2bf(v);
                else if (z == 1) Kb[(size_t)m * 512 + n] = f2bf(v);
                else {
                    int h = m >> 6, d = m & 63;
                    Vtb[(((size_t)bi * 8 + h) * 64 + d) * 784 + nn] = f2bf(v);
                }
            }
        }
    }
}

// ---------------- output projection, swapped (64x128 tiles): out[b][c][q] f32 -----
__global__ __launch_bounds__(256) void gemm_out(
    const unsigned short* __restrict__ Wto, const unsigned short* __restrict__ ctx,
    const float* __restrict__ bo, float* __restrict__ out)
{
    __shared__ unsigned short Als[64 * 32];
    __shared__ unsigned short Bls[128 * 32];
    int tid = threadIdx.x;
    int lane = tid & 63, wn = tid >> 6;
    int c16 = lane & 15, g = lane >> 4;
    int tm = blockIdx.x, tn = blockIdx.y;

    const unsigned short* Abase = Wto + (size_t)tm * 64 * 512;
    const unsigned short* Bbase = ctx + (size_t)tn * 128 * 512;

    floatx4 acc[4][2];
#pragma unroll
    for (int i = 0; i < 4; i++)
#pragma unroll
        for (int j = 0; j < 2; j++) acc[i][j] = (floatx4){0.f, 0.f, 0.f, 0.f};

    for (int kb = 0; kb < 16; ++kb) {
        int k0 = kb * 32;
        {
            int row = tid >> 2, kp = tid & 3;
            gl_lds16(Abase + (size_t)row * 512 + k0 + kp * 8, &Als[tid * 8]);
        }
#pragma unroll
        for (int rep = 0; rep < 2; ++rep) {
            int slot = rep * 256 + tid;
            int row = slot >> 2, kp = slot & 3;
            gl_lds16(Bbase + (size_t)row * 512 + k0 + kp * 8, &Bls[slot * 8]);
        }
        __syncthreads();
        short8 af[4], bfr[2];
#pragma unroll
        for (int i = 0; i < 4; i++)
            af[i] = *(const short8*)&Als[(i * 16 + c16) * 32 + g * 8];
#pragma unroll
        for (int j = 0; j < 2; j++)
            bfr[j] = *(const short8*)&Bls[(wn * 32 + j * 16 + c16) * 32 + g * 8];
#pragma unroll
        for (int i = 0; i < 4; i++)
#pragma unroll
            for (int j = 0; j < 2; j++)
                acc[i][j] = MFMA16(af[i], bfr[j], acc[i][j]);
        __syncthreads();
    }

#pragma unroll
    for (int j = 0; j < 2; j++) {
        int n = tn * 128 + wn * 32 + j * 16 + c16;
        int bi = n / 784, q = n - bi * 784;
#pragma unroll
        for (int i = 0; i < 4; i++) {
#pragma unroll
            for (int r4 = 0; r4 < 4; r4++) {
                int m = tm * 64 + i * 16 + g * 4 + r4;
                out[((size_t)bi * 512 + m) * 784 + q] = acc[i][j][r4] + bo[m];
            }
        }
    }
}

// ---------------- fused attention v4: LDS-staged K/V, one head per block ----------
// block = 256 thr = 4 waves; block owns (b, h, 128 q-rows); wave = 32 q-rows (2x16).
// K/V 64-key tiles double-buffered in LDS via global_load_lds (XOR col swizzle to
// kill the 128B-row-stride bank conflicts; swizzle applied to SOURCE address since
// the LDS destination of global_load_lds is fixed lane-contiguous).
// S^T = K·Q^T per 16x16 subtile => corr is one float4/lane, P-write one packed b64.
__global__ __launch_bounds__(256) void attn_kernel(
    const unsigned short* __restrict__ Qb,
    const unsigned short* __restrict__ Kb,
    const unsigned short* __restrict__ Vtb,
    const float* __restrict__ corr,
    unsigned short* __restrict__ ctx)
{
    __shared__ unsigned short Kls[2][4096];          // [buf][key(64)][dk(64)] swizzled
    __shared__ unsigned short Vls[2][4096];          // [buf][d(64)][key(64)] swizzled
    __shared__ unsigned short Plds[4 * 2 * 16 * 68]; // [wave][u][q(16)][key(64)+pad]

    int b = blockIdx.x, h = blockIdx.y, qt = blockIdx.z;
    int tid = threadIdx.x;
    int lane = tid & 63, w = tid >> 6;
    int c16 = lane & 15, g = lane >> 4;

    const unsigned short* Kh = Kb + (size_t)b * 784 * 512 + h * 64;
    const unsigned short* Vh = Vtb + ((size_t)(b * 8 + h)) * 64 * 784;

    int sr = tid >> 3, sc = tid & 7;   // staging: row 0..31 (x2), colblock 0..7

    auto stage = [&](int buf, int kt0) {
#pragma unroll
        for (int s = 0; s < 2; ++s) {
            int rr = s * 32 + sr;
            int cb = sc ^ (rr & 7);                    // XOR swizzle on source col
            int key = kt0 + rr; key = key < 784 ? key : 783;
            gl_lds16(Kh + (size_t)key * 512 + cb * 8, &Kls[buf][(s * 256 + tid) * 8]);
            int koff = kt0 + cb * 8; koff = koff <= 776 ? koff : 776;   // keep V reads in-range/finite
            gl_lds16(Vh + (size_t)rr * 784 + koff, &Vls[buf][(s * 256 + tid) * 8]);
        }
    };

    // Q fragments (B-operand of S^T): lane c16 = q, dk = g*8.. (+32)
    int q0 = qt * 128 + w * 32;
    short8 bq[2][2];
    const float* cq[2];
#pragma unroll
    for (int u = 0; u < 2; ++u) {
        int qr = q0 + u * 16 + c16; qr = qr < 784 ? qr : 783;
        const unsigned short* qp = Qb + (size_t)(b * 784 + qr) * 512 + h * 64 + g * 8;
        bq[u][0] = *(const short8*)qp;
        bq[u][1] = *(const short8*)(qp + 32);
        cq[u] = corr + ((size_t)b * 784 + qr) * 784;
    }

    floatx4 o[2][4];
    float l[2] = {0.f, 0.f};
#pragma unroll
    for (int u = 0; u < 2; ++u)
#pragma unroll
        for (int nt = 0; nt < 4; nt++) o[u][nt] = (floatx4){0.f, 0.f, 0.f, 0.f};

    unsigned short* Pw = &Plds[(size_t)w * 2 * 16 * 68];

    stage(0, 0);

#pragma unroll 1
    for (int it = 0; it < 13; ++it) {
        int cur = it & 1;
        int kt0 = it * 64;
        __syncthreads();                       // staging for `it` complete; prev reads done
        if (it < 12) stage(cur ^ 1, kt0 + 64); // prefetch next tile

        // --- S^T = K·Q^T per 16-key subtile, + exp, -> P (LDS) ---
#pragma unroll
        for (int t = 0; t < 4; ++t) {
            int kbase = kt0 + t * 16;          // wave-uniform
            if (kbase < 784) {
                int rr = t * 16 + c16;         // key row in tile
                short8 a0 = *(const short8*)&Kls[cur][rr * 64 + ((g ^ (rr & 7)) * 8)];
                short8 a1 = *(const short8*)&Kls[cur][rr * 64 + (((g + 4) ^ (rr & 7)) * 8)];
#pragma unroll
                for (int u = 0; u < 2; ++u) {
                    floatx4 st = (floatx4){0.f, 0.f, 0.f, 0.f};
                    st = MFMA16(a0, bq[u][0], st);
                    st = MFMA16(a1, bq[u][1], st);
                    float4 cv = *(const float4*)(cq[u] + kbase + g * 4);
                    float e0 = __expf(fmaf(st[0], 0.125f, cv.x));
                    float e1 = __expf(fmaf(st[1], 0.125f, cv.y));
                    float e2 = __expf(fmaf(st[2], 0.125f, cv.z));
                    float e3 = __expf(fmaf(st[3], 0.125f, cv.w));
                    l[u] += (e0 + e1) + (e2 + e3);
                    *(uint2*)&Pw[(u * 16 + c16) * 68 + t * 16 + g * 4] =
                        make_uint2(pack2bf(e0, e1), pack2bf(e2, e3));
                }
            } else {
#pragma unroll
                for (int u = 0; u < 2; ++u)
                    *(uint2*)&Pw[(u * 16 + c16) * 68 + t * 16 + g * 4] = make_uint2(0u, 0u);
            }
        }

        // --- P back as A-fragments (wave-private, in-order DS) ---
        short8 pa[2][2];
#pragma unroll
        for (int u = 0; u < 2; ++u) {
            const unsigned short* pr = &Pw[(u * 16 + c16) * 68];
            pa[u][0] = lds_read8(pr + g * 8);
            pa[u][1] = lds_read8(pr + 32 + g * 8);
        }

        // --- P·V from LDS V tile ---
#pragma unroll
        for (int nt = 0; nt < 4; ++nt) {
            int d = nt * 16 + c16;
            short8 v0 = *(const short8*)&Vls[cur][d * 64 + ((g ^ (d & 7)) * 8)];
            short8 v1 = *(const short8*)&Vls[cur][d * 64 + (((g + 4) ^ (d & 7)) * 8)];
            o[0][nt] = MFMA16(pa[0][0], v0, o[0][nt]);
            o[0][nt] = MFMA16(pa[0][1], v1, o[0][nt]);
            o[1][nt] = MFMA16(pa[1][0], v0, o[1][nt]);
            o[1][nt] = MFMA16(pa[1][1], v1, o[1][nt]);
        }
    }

    // normalize and store
#pragma unroll
    for (int u = 0; u < 2; ++u) {
        float lv = l[u];
        lv += __shfl_xor(lv, 16);
        lv += __shfl_xor(lv, 32);
        float inv = 1.0f / lv;
#pragma unroll
        for (int r = 0; r < 4; ++r) {
            float invr = __shfl(inv, g * 4 + r);
            int row = q0 + u * 16 + g * 4 + r;
            if (row < 784) {
#pragma unroll
                for (int nt = 0; nt < 4; ++nt)
                    ctx[(size_t)(b * 784 + row) * 512 + h * 64 + nt * 16 + c16] =
                        f2bf(o[u][nt][r] * invr);
            }
        }
    }
}

extern "C" void kernel_launch(void* const* d_in, const int* in_sizes, int n_in,
                              void* d_out, int out_size, void* d_ws, size_t ws_size,
                              hipStream_t stream) {
    (void)in_sizes; (void)n_in; (void)out_size;
    const float* queries = (const float*)d_in[0];
    const float* keys    = (const float*)d_in[1];
    const float* values  = (const float*)d_in[2];
    const float* corr    = (const float*)d_in[3];
    const float* Wq = (const float*)d_in[4];
    const float* bq = (const float*)d_in[5];
    const float* Wk = (const float*)d_in[6];
    const float* bk = (const float*)d_in[7];
    const float* Wv = (const float*)d_in[8];
    const float* bv = (const float*)d_in[9];
    const float* Wo = (const float*)d_in[10];
    const float* bo = (const float*)d_in[11];

    size_t need = (6 * SZX + 4 * WSEG) * 2;
    if (ws_size >= need) {
        unsigned short* Xq  = (unsigned short*)d_ws;     // later reused as ctx
        unsigned short* Xk  = Xq + SZX;
        unsigned short* Xv  = Xk + SZX;
        unsigned short* Qb  = Xv + SZX;
        unsigned short* Kb  = Qb + SZX;
        unsigned short* Vtb = Kb + SZX;
        unsigned short* Wt  = Vtb + SZX;

        transpose_cvt<<<dim3(16, 16, 4), dim3(32, 8), 0, stream>>>(Wq, Wk, Wv, Wo, Wt);
        cvt3<<<dim3(6272, 3), 256, 0, stream>>>(queries, keys, values, Xq, Xk, Xv, 0);
        gemm_qkv<<<dim3(98, 4, 3), 256, 0, stream>>>(Xq, Xk, Xv, Wt, bq, bk, bv, Qb, Kb, Vtb, 0);
        attn_kernel<<<dim3(16, 8, 7), 256, 0, stream>>>(Qb, Kb, Vtb, corr, Xq);
        gemm_out<<<dim3(8, 98), 256, 0, stream>>>(Wt + 3 * WSEG, Xq, bo, (float*)d_out);
    } else {
        // sequential fallback with a single shared X buffer
        unsigned short* X   = (unsigned short*)d_ws;
        unsigned short* Qb  = X + SZX;
        unsigned short* Kb  = Qb + SZX;
        unsigned short* Vtb = Kb + SZX;
        unsigned short* Wt  = Vtb + SZX;

        transpose_cvt<<<dim3(16, 16, 4), dim3(32, 8), 0, stream>>>(Wq, Wk, Wv, Wo, Wt);
        for (int z = 0; z < 3; ++z) {
            cvt3<<<dim3(6272, 1), 256, 0, stream>>>(queries, keys, values, X, X, X, z);
            gemm_qkv<<<dim3(98, 4, 1), 256, 0, stream>>>(X, X, X, Wt, bq, bk, bv, Qb, Kb, Vtb, z);
        }
        attn_kernel<<<dim3(16, 8, 7), 256, 0, stream>>>(Qb, Kb, Vtb, corr, X);
        gemm_out<<<dim3(8, 98), 256, 0, stream>>>(Wt + 3 * WSEG, X, bo, (float*)d_out);
    }
}

// Round 7
// 333.513 us; speedup vs baseline: 1.1862x; 1.0182x over previous
//
#include <hip/hip_runtime.h>
#include <hip/hip_bf16.h>

// B=16, NQ=NK=784, D_MODEL=512, H=8, DK=DV=64
#define SZX ((size_t)12544 * 512)   // elements of one [B*784, 512] matrix
#define WSEG ((size_t)262144)       // one 512x512 weight

typedef __attribute__((ext_vector_type(8))) short short8;
typedef __attribute__((ext_vector_type(4))) short short4s;
typedef __attribute__((ext_vector_type(4))) float floatx4;

typedef const __attribute__((address_space(1))) void* gas_cvp;
typedef __attribute__((address_space(3))) void* las_vp;

__device__ __forceinline__ void gl_lds16(const void* g, void* l) {
    __builtin_amdgcn_global_load_lds((gas_cvp)g, (las_vp)l, 16, 0, 0);
}

__device__ __forceinline__ unsigned short f2bf(float f) {
    unsigned int u = __float_as_uint(f);
    u += 0x7fffu + ((u >> 16) & 1u);   // RNE
    return (unsigned short)(u >> 16);
}

__device__ __forceinline__ unsigned int pack2bf(float a, float b) {
    __hip_bfloat162 h = __float22bfloat162_rn(float2{a, b});  // v_cvt_pk_bf16_f32
    return *(unsigned int*)&h;
}

__device__ __forceinline__ short8 pack8(float4 a, float4 b) {
    union { unsigned int u[4]; short8 s; } r;
    r.u[0] = pack2bf(a.x, a.y);
    r.u[1] = pack2bf(a.z, a.w);
    r.u[2] = pack2bf(b.x, b.y);
    r.u[3] = pack2bf(b.z, b.w);
    return r.s;
}

__device__ __forceinline__ short8 lds_read8(const unsigned short* p) {
    // 8B-aligned LDS read as two b64s (measured 0 bank conflicts R2-R4)
    short4s a = *(const short4s*)p;
    short4s b = *(const short4s*)(p + 4);
    return __builtin_shufflevector(a, b, 0, 1, 2, 3, 4, 5, 6, 7);
}

#define MFMA16(a, b, c) __builtin_amdgcn_mfma_f32_16x16x32_bf16(a, b, c, 0, 0, 0)

// ---------------- weight transpose + convert: Wt[o][i] = bf16(W[i][o]) ------------
__global__ void transpose_cvt(const float* __restrict__ W0, const float* __restrict__ W1,
                              const float* __restrict__ W2, const float* __restrict__ W3,
                              unsigned short* __restrict__ out) {
    __shared__ float tile[32][33];
    const float* W = blockIdx.z == 0 ? W0 : blockIdx.z == 1 ? W1 : blockIdx.z == 2 ? W2 : W3;
    unsigned short* O = out + (size_t)blockIdx.z * WSEG;
    int x = blockIdx.x * 32 + threadIdx.x;
    int y0 = blockIdx.y * 32;
    for (int k = threadIdx.y; k < 32; k += 8)
        tile[k][threadIdx.x] = W[(size_t)(y0 + k) * 512 + x];
    __syncthreads();
    int xo = blockIdx.y * 32 + threadIdx.x;
    int yo0 = blockIdx.x * 32;
    for (int k = threadIdx.y; k < 32; k += 8)
        O[(size_t)(yo0 + k) * 512 + xo] = f2bf(tile[threadIdx.x][k]);
}

// ---------------- merged QKV projection GEMM, f32 X staged in-kernel --------------
// z=0: Qb[row][512] = bf16(Xq) @ Wtq^T + bq   (A = X side, B = W side)
// z=1: Kb likewise
// z=2: Vt[(b*8+h)*64+d][n] computed swapped: A = Wtv, B = bf16(Xv)
// X-side tile staged manually: f32 loads -> v_cvt_pk_bf16_f32 -> ds_write_b128 at
// the same lane-linear slot*8 layout global_load_lds produces (2-way bank = free).
__global__ __launch_bounds__(256) void gemm_qkv(
    const float* __restrict__ Xq, const float* __restrict__ Xk,
    const float* __restrict__ Xv, const unsigned short* __restrict__ Wt,
    const float* __restrict__ bq, const float* __restrict__ bk, const float* __restrict__ bv,
    unsigned short* __restrict__ Qb, unsigned short* __restrict__ Kb,
    unsigned short* __restrict__ Vtb)
{
    __shared__ unsigned short Als[128 * 32];
    __shared__ unsigned short Bls[128 * 32];
    int z = blockIdx.z;
    const float* X = z == 0 ? Xq : z == 1 ? Xk : Xv;
    const unsigned short* Wz = Wt + (size_t)z * WSEG;
    const float* bias = z == 0 ? bq : z == 1 ? bk : bv;

    int tid = threadIdx.x;
    int lane = tid & 63, wave = tid >> 6;
    int wm = wave & 1, wn = wave >> 1;
    int c16 = lane & 15, g = lane >> 4;

    int xt = blockIdx.x;            // X-side tile (12544/128 = 98)
    int wtile = blockIdx.y;         // W-side tile (512/128 = 4)
    const float* Xbase = X + (size_t)xt * 128 * 512;
    const unsigned short* Wbase = Wz + (size_t)wtile * 128 * 512;

    // operand roles: z<2 -> A=X,B=W ; z==2 -> A=W,B=X
    unsigned short* Xls = (z < 2) ? Als : Bls;
    unsigned short* Wls = (z < 2) ? Bls : Als;
    int tm = (z < 2) ? xt : wtile;
    int tn = (z < 2) ? wtile : xt;

    // X f32 source pointers (slot = rep*256+tid -> row, k-part)
    const float* xsrc[2];
#pragma unroll
    for (int rep = 0; rep < 2; ++rep) {
        int slot = rep * 256 + tid;
        xsrc[rep] = Xbase + (size_t)(slot >> 2) * 512 + (slot & 3) * 8;
    }

    float4 xr[2][2];
#pragma unroll
    for (int rep = 0; rep < 2; ++rep) {
        xr[rep][0] = *(const float4*)(xsrc[rep]);
        xr[rep][1] = *(const float4*)(xsrc[rep] + 4);
    }

    floatx4 acc[4][4];
#pragma unroll
    for (int i = 0; i < 4; i++)
#pragma unroll
        for (int j = 0; j < 4; j++) acc[i][j] = (floatx4){0.f, 0.f, 0.f, 0.f};

    for (int kb = 0; kb < 16; ++kb) {
        int k0 = kb * 32;
        // stage X tile from registers (convert f32 -> bf16)
#pragma unroll
        for (int rep = 0; rep < 2; ++rep) {
            int slot = rep * 256 + tid;
            *(short8*)&Xls[slot * 8] = pack8(xr[rep][0], xr[rep][1]);
        }
        // stage W tile via global_load_lds
#pragma unroll
        for (int rep = 0; rep < 2; ++rep) {
            int slot = rep * 256 + tid;
            gl_lds16(Wbase + (size_t)(slot >> 2) * 512 + k0 + (slot & 3) * 8, &Wls[slot * 8]);
        }
        __syncthreads();
        // prefetch next X f32 during the MFMA phase
        if (kb < 15) {
#pragma unroll
            for (int rep = 0; rep < 2; ++rep) {
                xr[rep][0] = *(const float4*)(xsrc[rep] + (kb + 1) * 32);
                xr[rep][1] = *(const float4*)(xsrc[rep] + (kb + 1) * 32 + 4);
            }
        }
        short8 af[4], bfr[4];
#pragma unroll
        for (int i = 0; i < 4; i++)
            af[i] = *(const short8*)&Als[(wm * 64 + i * 16 + c16) * 32 + g * 8];
#pragma unroll
        for (int j = 0; j < 4; j++)
            bfr[j] = *(const short8*)&Bls[(wn * 64 + j * 16 + c16) * 32 + g * 8];
#pragma unroll
        for (int i = 0; i < 4; i++)
#pragma unroll
            for (int j = 0; j < 4; j++)
                acc[i][j] = MFMA16(af[i], bfr[j], acc[i][j]);
        __syncthreads();
    }

#pragma unroll
    for (int j = 0; j < 4; j++) {
        int n = tn * 128 + wn * 64 + j * 16 + c16;
        int bi = n / 784, nn = n - bi * 784;         // z==2 only
#pragma unroll
        for (int i = 0; i < 4; i++) {
#pragma unroll
            for (int r4 = 0; r4 < 4; r4++) {
                int m = tm * 128 + wm * 64 + i * 16 + g * 4 + r4;
                float v = acc[i][j][r4] + ((z < 2) ? bias[n] : bias[m]);
                if (z == 0)      Qb[(size_t)m * 512 + n] = f2bf(v);
                else if (z == 1) Kb[(size_t)m * 512 + n] = f2bf(v);
                else {
                    int h = m >> 6, d = m & 63;
                    Vtb[(((size_t)bi * 8 + h) * 64 + d) * 784 + nn] = f2bf(v);
                }
            }
        }
    }
}

// ---------------- output projection, swapped (64x128 tiles): out[b][c][q] f32 -----
__global__ __launch_bounds__(256) void gemm_out(
    const unsigned short* __restrict__ Wto, const unsigned short* __restrict__ ctx,
    const float* __restrict__ bo, float* __restrict__ out)
{
    __shared__ unsigned short Als[64 * 32];
    __shared__ unsigned short Bls[128 * 32];
    int tid = threadIdx.x;
    int lane = tid & 63, wn = tid >> 6;
    int c16 = lane & 15, g = lane >> 4;
    int tm = blockIdx.x, tn = blockIdx.y;

    const unsigned short* Abase = Wto + (size_t)tm * 64 * 512;
    const unsigned short* Bbase = ctx + (size_t)tn * 128 * 512;

    floatx4 acc[4][2];
#pragma unroll
    for (int i = 0; i < 4; i++)
#pragma unroll
        for (int j = 0; j < 2; j++) acc[i][j] = (floatx4){0.f, 0.f, 0.f, 0.f};

    for (int kb = 0; kb < 16; ++kb) {
        int k0 = kb * 32;
        {
            int row = tid >> 2, kp = tid & 3;
            gl_lds16(Abase + (size_t)row * 512 + k0 + kp * 8, &Als[tid * 8]);
        }
#pragma unroll
        for (int rep = 0; rep < 2; ++rep) {
            int slot = rep * 256 + tid;
            int row = slot >> 2, kp = slot & 3;
            gl_lds16(Bbase + (size_t)row * 512 + k0 + kp * 8, &Bls[slot * 8]);
        }
        __syncthreads();
        short8 af[4], bfr[2];
#pragma unroll
        for (int i = 0; i < 4; i++)
            af[i] = *(const short8*)&Als[(i * 16 + c16) * 32 + g * 8];
#pragma unroll
        for (int j = 0; j < 2; j++)
            bfr[j] = *(const short8*)&Bls[(wn * 32 + j * 16 + c16) * 32 + g * 8];
#pragma unroll
        for (int i = 0; i < 4; i++)
#pragma unroll
            for (int j = 0; j < 2; j++)
                acc[i][j] = MFMA16(af[i], bfr[j], acc[i][j]);
        __syncthreads();
    }

#pragma unroll
    for (int j = 0; j < 2; j++) {
        int n = tn * 128 + wn * 32 + j * 16 + c16;
        int bi = n / 784, q = n - bi * 784;
#pragma unroll
        for (int i = 0; i < 4; i++) {
#pragma unroll
            for (int r4 = 0; r4 < 4; r4++) {
                int m = tm * 64 + i * 16 + g * 4 + r4;
                out[((size_t)bi * 512 + m) * 784 + q] = acc[i][j][r4] + bo[m];
            }
        }
    }
}

// ---------------- fused attention v4 (known-good, reverted verbatim) --------------
// block = 256 thr = 4 waves; block owns (b, h, 128 q-rows); wave = 32 q-rows (2x16).
// K/V 64-key tiles double-buffered in LDS via global_load_lds (XOR col swizzle).
// S^T = K·Q^T per 16x16 subtile => corr is one float4/lane, P-write one packed b64.
__global__ __launch_bounds__(256) void attn_kernel(
    const unsigned short* __restrict__ Qb,
    const unsigned short* __restrict__ Kb,
    const unsigned short* __restrict__ Vtb,
    const float* __restrict__ corr,
    unsigned short* __restrict__ ctx)
{
    __shared__ unsigned short Kls[2][4096];          // [buf][key(64)][dk(64)] swizzled
    __shared__ unsigned short Vls[2][4096];          // [buf][d(64)][key(64)] swizzled
    __shared__ unsigned short Plds[4 * 2 * 16 * 68]; // [wave][u][q(16)][key(64)+pad]

    int b = blockIdx.x, h = blockIdx.y, qt = blockIdx.z;
    int tid = threadIdx.x;
    int lane = tid & 63, w = tid >> 6;
    int c16 = lane & 15, g = lane >> 4;

    const unsigned short* Kh = Kb + (size_t)b * 784 * 512 + h * 64;
    const unsigned short* Vh = Vtb + ((size_t)(b * 8 + h)) * 64 * 784;

    int sr = tid >> 3, sc = tid & 7;   // staging: row 0..31 (x2), colblock 0..7

    auto stage = [&](int buf, int kt0) {
#pragma unroll
        for (int s = 0; s < 2; ++s) {
            int rr = s * 32 + sr;
            int cb = sc ^ (rr & 7);                    // XOR swizzle on source col
            int key = kt0 + rr; key = key < 784 ? key : 783;
            gl_lds16(Kh + (size_t)key * 512 + cb * 8, &Kls[buf][(s * 256 + tid) * 8]);
            int koff = kt0 + cb * 8; koff = koff <= 776 ? koff : 776;   // tail-safe
            gl_lds16(Vh + (size_t)rr * 784 + koff, &Vls[buf][(s * 256 + tid) * 8]);
        }
    };

    // Q fragments (B-operand of S^T): lane c16 = q, dk = g*8.. (+32)
    int q0 = qt * 128 + w * 32;
    short8 bq[2][2];
    const float* cq[2];
#pragma unroll
    for (int u = 0; u < 2; ++u) {
        int qr = q0 + u * 16 + c16; qr = qr < 784 ? qr : 783;
        const unsigned short* qp = Qb + (size_t)(b * 784 + qr) * 512 + h * 64 + g * 8;
        bq[u][0] = *(const short8*)qp;
        bq[u][1] = *(const short8*)(qp + 32);
        cq[u] = corr + ((size_t)b * 784 + qr) * 784;
    }

    floatx4 o[2][4];
    float l[2] = {0.f, 0.f};
#pragma unroll
    for (int u = 0; u < 2; ++u)
#pragma unroll
        for (int nt = 0; nt < 4; nt++) o[u][nt] = (floatx4){0.f, 0.f, 0.f, 0.f};

    unsigned short* Pw = &Plds[(size_t)w * 2 * 16 * 68];

    stage(0, 0);

#pragma unroll 1
    for (int it = 0; it < 13; ++it) {
        int cur = it & 1;
        int kt0 = it * 64;
        __syncthreads();                       // staging for `it` complete; prev reads done
        if (it < 12) stage(cur ^ 1, kt0 + 64); // prefetch next tile

        // --- S^T = K·Q^T per 16-key subtile, + exp, -> P (LDS) ---
#pragma unroll
        for (int t = 0; t < 4; ++t) {
            int kbase = kt0 + t * 16;          // wave-uniform
            if (kbase < 784) {
                int rr = t * 16 + c16;         // key row in tile
                short8 a0 = *(const short8*)&Kls[cur][rr * 64 + ((g ^ (rr & 7)) * 8)];
                short8 a1 = *(const short8*)&Kls[cur][rr * 64 + (((g + 4) ^ (rr & 7)) * 8)];
#pragma unroll
                for (int u = 0; u < 2; ++u) {
                    floatx4 st = (floatx4){0.f, 0.f, 0.f, 0.f};
                    st = MFMA16(a0, bq[u][0], st);
                    st = MFMA16(a1, bq[u][1], st);
                    float4 cv = *(const float4*)(cq[u] + kbase + g * 4);
                    float e0 = __expf(fmaf(st[0], 0.125f, cv.x));
                    float e1 = __expf(fmaf(st[1], 0.125f, cv.y));
                    float e2 = __expf(fmaf(st[2], 0.125f, cv.z));
                    float e3 = __expf(fmaf(st[3], 0.125f, cv.w));
                    l[u] += (e0 + e1) + (e2 + e3);
                    *(uint2*)&Pw[(u * 16 + c16) * 68 + t * 16 + g * 4] =
                        make_uint2(pack2bf(e0, e1), pack2bf(e2, e3));
                }
            } else {
#pragma unroll
                for (int u = 0; u < 2; ++u)
                    *(uint2*)&Pw[(u * 16 + c16) * 68 + t * 16 + g * 4] = make_uint2(0u, 0u);
            }
        }

        // --- P back as A-fragments (wave-private, in-order DS) ---
        short8 pa[2][2];
#pragma unroll
        for (int u = 0; u < 2; ++u) {
            const unsigned short* pr = &Pw[(u * 16 + c16) * 68];
            pa[u][0] = lds_read8(pr + g * 8);
            pa[u][1] = lds_read8(pr + 32 + g * 8);
        }

        // --- P·V from LDS V tile ---
#pragma unroll
        for (int nt = 0; nt < 4; ++nt) {
            int d = nt * 16 + c16;
            short8 v0 = *(const short8*)&Vls[cur][d * 64 + ((g ^ (d & 7)) * 8)];
            short8 v1 = *(const short8*)&Vls[cur][d * 64 + (((g + 4) ^ (d & 7)) * 8)];
            o[0][nt] = MFMA16(pa[0][0], v0, o[0][nt]);
            o[0][nt] = MFMA16(pa[0][1], v1, o[0][nt]);
            o[1][nt] = MFMA16(pa[1][0], v0, o[1][nt]);
            o[1][nt] = MFMA16(pa[1][1], v1, o[1][nt]);
        }
    }

    // normalize and store (guarded against the 896>784 tail)
#pragma unroll
    for (int u = 0; u < 2; ++u) {
        float lv = l[u];
        lv += __shfl_xor(lv, 16);
        lv += __shfl_xor(lv, 32);
        float inv = 1.0f / lv;
#pragma unroll
        for (int r = 0; r < 4; ++r) {
            float invr = __shfl(inv, g * 4 + r);
            int row = q0 + u * 16 + g * 4 + r;
            if (row < 784) {
#pragma unroll
                for (int nt = 0; nt < 4; ++nt)
                    ctx[(size_t)(b * 784 + row) * 512 + h * 64 + nt * 16 + c16] =
                        f2bf(o[u][nt][r] * invr);
            }
        }
    }
}

extern "C" void kernel_launch(void* const* d_in, const int* in_sizes, int n_in,
                              void* d_out, int out_size, void* d_ws, size_t ws_size,
                              hipStream_t stream) {
    (void)in_sizes; (void)n_in; (void)out_size; (void)ws_size;
    const float* queries = (const float*)d_in[0];
    const float* keys    = (const float*)d_in[1];
    const float* values  = (const float*)d_in[2];
    const float* corr    = (const float*)d_in[3];
    const float* Wq = (const float*)d_in[4];
    const float* bq = (const float*)d_in[5];
    const float* Wk = (const float*)d_in[6];
    const float* bk = (const float*)d_in[7];
    const float* Wv = (const float*)d_in[8];
    const float* bv = (const float*)d_in[9];
    const float* Wo = (const float*)d_in[10];
    const float* bo = (const float*)d_in[11];

    unsigned short* Qb  = (unsigned short*)d_ws;
    unsigned short* Kb  = Qb + SZX;
    unsigned short* Vtb = Kb + SZX;
    unsigned short* ctx = Vtb + SZX;
    unsigned short* Wt  = ctx + SZX;   // 4 x [512][512] bf16 (BT layout)

    transpose_cvt<<<dim3(16, 16, 4), dim3(32, 8), 0, stream>>>(Wq, Wk, Wv, Wo, Wt);
    gemm_qkv<<<dim3(98, 4, 3), 256, 0, stream>>>(queries, keys, values, Wt,
                                                 bq, bk, bv, Qb, Kb, Vtb);
    attn_kernel<<<dim3(16, 8, 7), 256, 0, stream>>>(Qb, Kb, Vtb, corr, ctx);
    gemm_out<<<dim3(8, 98), 256, 0, stream>>>(Wt + 3 * WSEG, ctx, bo, (float*)d_out);
}